// Round 7
// baseline (240.950 us; speedup 1.0000x reference)
//
#include <hip/hip_runtime.h>

#define B_  4
#define NN_ 20
#define C_  128
#define H_  8
#define W_  32
#define P_  256      // H*W
#define GS_ 32
#define L_  1024     // GS*GS
#define K_  5120     // NN*P

// ---------------- ws layout (float elements) ----------------
// ind   : int   [B*L*NN]   @ 0         (81920)
// Kscal : float [B*L*NN]   @ 81920     (81920)
// Rc    : float [360*P]    @ 163840    (92160)
// Pc    : float [B*NN*P]   @ 256000    (20480)
// pano  : float [B*NN*2*P] @ 276480    (40960)
// ovmax : float [B*L]      @ 317440    (4096)
// ovmean: float [B*L]      @ 321536    (4096)
// Ft    : float [B*K*C]    @ 325632    (2621440)
// part  : float [NS*B*L*C] @ 2947072   (NS*524288); NS=8 if ws fits (28.6MB), else 4

// ---- fused front-end A: pano (80 blk) + overhead (16 blk) + rays conv (360 blk)
__global__ __launch_bounds__(256) void k_fa(const float* __restrict__ feats,
                                            const float* __restrict__ over,
                                            const float* __restrict__ rays,
                                            const float* __restrict__ w1,
                                            const float* __restrict__ w2,
                                            const float* __restrict__ fw,
                                            float* __restrict__ pano,
                                            float* __restrict__ ovmax,
                                            float* __restrict__ ovmean,
                                            float* __restrict__ Rc) {
  __shared__ float s[3 * P_];
  int bid = blockIdx.x, tid = threadIdx.x;
  if (bid < 80) {
    int t = bid * 256 + tid;                     // B*NN*P = 20480
    int p = t & 255, bn = t >> 8;
    const float* src = feats + bn * C_ * P_ + p;
    float mx = -3.4e38f, sm = 0.f;
    #pragma unroll 8
    for (int c = 0; c < C_; ++c) { float v = src[c * P_]; mx = fmaxf(mx, v); sm += v; }
    pano[(bn * 2 + 0) * P_ + p] = mx;
    pano[(bn * 2 + 1) * P_ + p] = sm * (1.0f / 128.0f);
  } else if (bid < 96) {
    int t = (bid - 80) * 256 + tid;              // B*L = 4096
    int b = t >> 10, l = t & 1023;
    const float* src = over + b * C_ * L_ + l;
    float mx = -3.4e38f, sm = 0.f;
    #pragma unroll 8
    for (int c = 0; c < C_; ++c) { float v = src[c * L_]; mx = fmaxf(mx, v); sm += v; }
    ovmax[t] = mx; ovmean[t] = sm * (1.0f / 128.0f);
  } else {
    int a = bid - 96;                            // 360 angles
    #pragma unroll
    for (int c = 0; c < 3; ++c) s[c * P_ + tid] = rays[(a * 3 + c) * P_ + tid];
    __syncthreads();
    int y = tid >> 5, x = tid & 31;
    float acc1 = 0.f, acc2 = 0.f;
    #pragma unroll
    for (int c = 0; c < 3; ++c) {
      const float* sc  = s + c * P_;
      const float* w1c = w1 + (1 + c) * 9;
      const float* w2c = w2 + (1 + c) * 25;
      #pragma unroll
      for (int dy = 0; dy < 3; ++dy) { int yy = ((y + dy + 7) & 7) * 32;
        #pragma unroll
        for (int dx = 0; dx < 3; ++dx) { int xx = (x + dx + 31) & 31;
          acc1 += sc[yy + xx] * w1c[dy * 3 + dx]; } }
      #pragma unroll
      for (int dy = 0; dy < 5; ++dy) { int yy = ((y + dy + 6) & 7) * 32;
        #pragma unroll
        for (int dx = 0; dx < 5; ++dx) { int xx = (x + dx + 30) & 31;
          acc2 += sc[yy + xx] * w2c[dy * 5 + dx]; } }
    }
    Rc[a * P_ + tid] = fw[0] * acc1 + fw[1] * acc2;
  }
}

// ---- fused front-end B: pano conv (80 blk) + geo (320 blk) + feats transpose (320 blk)
__global__ __launch_bounds__(256) void k_fb(const float* __restrict__ pano,
                                            const float* __restrict__ bbox,
                                            const float* __restrict__ locs,
                                            const float* __restrict__ ovmax,
                                            const float* __restrict__ ovmean,
                                            const float* __restrict__ feats,
                                            const float* __restrict__ w1,
                                            const float* __restrict__ w2,
                                            const float* __restrict__ b1,
                                            const float* __restrict__ b2,
                                            const float* __restrict__ fw,
                                            const float* __restrict__ fb,
                                            float* __restrict__ Pc,
                                            int* __restrict__ ind,
                                            float* __restrict__ Kscal,
                                            float* __restrict__ Ft) {
  __shared__ float s[32 * 257];
  int bid = blockIdx.x, tid = threadIdx.x;
  if (bid < 80) {
    int bn = bid;
    s[tid]      = pano[(bn * 2 + 0) * P_ + tid];
    s[P_ + tid] = pano[(bn * 2 + 1) * P_ + tid];
    __syncthreads();
    int y = tid >> 5, x = tid & 31;
    float acc1 = 0.f, acc2 = 0.f;
    #pragma unroll
    for (int c = 0; c < 2; ++c) {
      const float* sc  = s + c * P_;
      const float* w1c = w1 + (4 + c) * 9;
      const float* w2c = w2 + (4 + c) * 25;
      #pragma unroll
      for (int dy = 0; dy < 3; ++dy) { int yy = ((y + dy + 7) & 7) * 32;
        #pragma unroll
        for (int dx = 0; dx < 3; ++dx) { int xx = (x + dx + 31) & 31;
          acc1 += sc[yy + xx] * w1c[dy * 3 + dx]; } }
      #pragma unroll
      for (int dy = 0; dy < 5; ++dy) { int yy = ((y + dy + 6) & 7) * 32;
        #pragma unroll
        for (int dx = 0; dx < 5; ++dx) { int xx = (x + dx + 30) & 31;
          acc2 += sc[yy + xx] * w2c[dy * 5 + dx]; } }
    }
    Pc[bn * P_ + tid] = fw[0] * acc1 + fw[1] * acc2;
  } else if (bid < 400) {
    int t = (bid - 80) * 256 + tid;              // B*L*NN = 81920
    int n = t % NN_;
    int r = t / NN_;                             // b*L + l
    int l = r & 1023, b = r >> 10;
    int i = l >> 5, j = l & 31;
    float y0 = bbox[b * 4 + 0], x0 = bbox[b * 4 + 1];
    float y1 = bbox[b * 4 + 2], x1 = bbox[b * 4 + 3];
    float gy = (i == 31) ? y1 : (y0 + ((y1 - y0) / 31.0f) * (float)i);
    float gx = (j == 31) ? x1 : (x0 + ((x1 - x0) / 31.0f) * (float)j);
    float d0 = gy - locs[(b * NN_ + n) * 2 + 0];
    float d1 = gx - locs[(b * NN_ + n) * 2 + 1];
    float D  = sqrtf(d0 * d0 + d1 * d1 + 1e-12f);
    float th = atan2f(d1, d0);
    if (th < 0.f) th += 6.283185307179586f;
    float deg = th * 57.29577951308232f;
    int di = (int)rintf(deg);
    if (di >= 360) di -= 360;
    float s10 = 0, s16 = 0, s17 = 0;
    #pragma unroll
    for (int q = 0; q < 9; ++q) { s10 += w1[q]; s16 += w1[54 + q]; s17 += w1[63 + q]; }
    float s20 = 0, s26 = 0, s27 = 0;
    #pragma unroll
    for (int q = 0; q < 25; ++q) { s20 += w2[q]; s26 += w2[150 + q]; s27 += w2[175 + q]; }
    float om = ovmax[r], oa = ovmean[r];
    ind[t]   = di;
    Kscal[t] = fw[0] * (D * s10 + om * s16 + oa * s17 + b1[0])
             + fw[1] * (D * s20 + om * s26 + oa * s27 + b2[0]) + fb[0];
  } else {
    int bb = bid - 400;                          // 320 = (b*NN+n)*4 + c-quarter
    int bn = bb >> 2, cq = bb & 3;
    int b = bn / NN_, n = bn % NN_;
    int c0 = cq * 32;
    #pragma unroll 4
    for (int cc = 0; cc < 32; ++cc)
      s[cc * 257 + tid] = feats[(bn * C_ + c0 + cc) * P_ + tid];
    __syncthreads();
    int c = tid & 31, p8 = tid >> 5;
    #pragma unroll 4
    for (int pp = 0; pp < 32; ++pp) {
      int p = pp * 8 + p8;
      Ft[((size_t)b * K_ + n * P_ + p) * C_ + c0 + c] = s[c * 257 + p];
    }
  }
}

// Per grid cell: assemble logits, softmax over (n,p)=5120, write fp32 attn.
__global__ __launch_bounds__(256) void k_soft(const float* __restrict__ Rc,
                                              const float* __restrict__ Pc,
                                              const float* __restrict__ Kscal,
                                              const int* __restrict__ ind,
                                              float* __restrict__ attn) {
  int bl = blockIdx.x;                           // b*L + l
  int b = bl >> 10;
  int tid = threadIdx.x;                         // pixel p
  __shared__ float sK[NN_];
  __shared__ int   sI[NN_];
  __shared__ float red[8];                       // [0..3]=max, [4..7]=sum
  if (tid < NN_) { sI[tid] = ind[bl * NN_ + tid]; sK[tid] = Kscal[bl * NN_ + tid]; }
  __syncthreads();
  float lg[NN_];
  #pragma unroll
  for (int n = 0; n < NN_; ++n)
    lg[n] = Rc[sI[n] * P_ + tid] + Pc[(b * NN_ + n) * P_ + tid] + sK[n];
  float m = -3.4e38f;
  #pragma unroll
  for (int n = 0; n < NN_; ++n) m = fmaxf(m, lg[n]);
  #pragma unroll
  for (int off = 32; off > 0; off >>= 1) m = fmaxf(m, __shfl_xor(m, off));
  if ((tid & 63) == 0) red[tid >> 6] = m;
  __syncthreads();
  m = fmaxf(fmaxf(red[0], red[1]), fmaxf(red[2], red[3]));
  float ssum = 0.f;
  #pragma unroll
  for (int n = 0; n < NN_; ++n) { lg[n] = expf(lg[n] - m); ssum += lg[n]; }
  #pragma unroll
  for (int off = 32; off > 0; off >>= 1) ssum += __shfl_xor(ssum, off);
  if ((tid & 63) == 0) red[4 + (tid >> 6)] = ssum;
  __syncthreads();
  float inv = 1.0f / ((red[4] + red[5]) + (red[6] + red[7]));
  #pragma unroll
  for (int n = 0; n < NN_; ++n)
    attn[((size_t)bl * NN_ + n) * P_ + tid] = lg[n] * inv;
}

// part[ks][b,l,c] = sum_{k in split ks} attn[b,l,k] * Ft[b,k,c]
// Grid = 4b x 32lt x NS; 256 thr = 4 waves; tile 32 l x 128 c x (K/NS) k.
// Wave w owns l = l0+8w..+7. Lane = (q = lane>>4 k-offset, cg = lane&15 -> c).
// r6 lesson: VGPR=84 left no room to pipeline -> every 4-k step serialized
// load-latency (~200cy) vs 128cy FMA; all pipes <50%, extra waves didn't help.
// Fix: __launch_bounds__(256,4) (<=128 VGPR) + hand-written 2-stage register
// pipeline (A/B named sets, static indices): step i+1's 2 ds_read_b128 +
// 2 global_dwordx4 issue BEFORE step i's 64 FMAs -> latency hides in-wave.
// Same per-step accumulation order as r4/r6 -> bitwise-identical output.
template<int NSH>
__global__ __launch_bounds__(256, 4) void k_mm(const float* __restrict__ attn,
                                               const float* __restrict__ Ft,
                                               float* __restrict__ part) {
  constexpr int NS = 1 << NSH;
  constexpr int KC = K_ / NS;                    // k per block
  __shared__ __align__(16) float sW[128 * 36];   // sW[k][l], stride 36: b128 align
  int bid = blockIdx.x;
  int ks = bid & (NS - 1);
  int lt = (bid >> NSH) & 31;
  int b  = bid >> (NSH + 5);
  int l0 = lt << 5;                              // 32 l per block
  int kbase = ks * KC;
  int tid = threadIdx.x;
  int w8 = (tid >> 6) << 3;                      // wave * 8 -> l offset
  int lane = tid & 63;
  int q  = lane >> 4;                            // 0..3 : k offset within 4-k step
  int c0 = (lane & 15) << 2;                     // c 0..60 (lo half), +64 (hi half)
  int kst = tid & 127, hst = tid >> 7;           // staging role: k, l-half
  float4 aL[8], aH[8];
  #pragma unroll
  for (int r = 0; r < 8; ++r) {
    aL[r] = make_float4(0.f, 0.f, 0.f, 0.f);
    aH[r] = make_float4(0.f, 0.f, 0.f, 0.f);
  }
  const float* arow  = attn + ((size_t)b * L_ + l0) * K_ + kbase;
  const float* fbase = Ft + ((size_t)b * K_ + kbase + q) * C_ + c0;
  for (int kc0 = 0; kc0 < KC; kc0 += 128) {
    __syncthreads();                             // all waves done reading sW
    #pragma unroll
    for (int r = 0; r < 16; ++r)                 // 128 k x 32 l, 16 elems/thread
      sW[kst * 36 + hst * 16 + r] = arow[(size_t)(hst * 16 + r) * K_ + kc0 + kst];
    __syncthreads();
    const float* fp  = fbase + (size_t)kc0 * C_;
    const float* swk = sW + q * 36 + w8;
    // ---- 2-stage software pipeline over the 32 4-k steps ----
    float4 wa0 = *(const float4*)(swk);
    float4 wb0 = *(const float4*)(swk + 4);
    float4 fa0 = *(const float4*)(fp);
    float4 fb0 = *(const float4*)(fp + 64);
#define FMA8(r, wgt, f0, f1) \
    aL[r].x += (wgt) * f0.x; aL[r].y += (wgt) * f0.y; \
    aL[r].z += (wgt) * f0.z; aL[r].w += (wgt) * f0.w; \
    aH[r].x += (wgt) * f1.x; aH[r].y += (wgt) * f1.y; \
    aH[r].z += (wgt) * f1.z; aH[r].w += (wgt) * f1.w;
#define FMA64(wa, wb, f0, f1) \
    FMA8(0, wa.x, f0, f1) FMA8(1, wa.y, f0, f1) FMA8(2, wa.z, f0, f1) \
    FMA8(3, wa.w, f0, f1) FMA8(4, wb.x, f0, f1) FMA8(5, wb.y, f0, f1) \
    FMA8(6, wb.z, f0, f1) FMA8(7, wb.w, f0, f1)
    #pragma unroll
    for (int kk = 0; kk < 128; kk += 8) {
      // prefetch step kk+4 into B set (before A's FMAs)
      float4 wa1 = *(const float4*)(swk + (kk + 4) * 36);
      float4 wb1 = *(const float4*)(swk + (kk + 4) * 36 + 4);
      float4 fa1 = *(const float4*)(fp + (size_t)(kk + 4) * C_);
      float4 fb1 = *(const float4*)(fp + (size_t)(kk + 4) * C_ + 64);
      FMA64(wa0, wb0, fa0, fb0)
      // prefetch step kk+8 into A set (compile-time-clamped at tail; the
      // clamped reload of step 0 is in-bounds and its values are unused)
      {
        constexpr int dummy = 0; (void)dummy;
      }
      int pk = (kk + 8 < 128) ? (kk + 8) : 0;    // folds at compile time
      wa0 = *(const float4*)(swk + pk * 36);
      wb0 = *(const float4*)(swk + pk * 36 + 4);
      fa0 = *(const float4*)(fp + (size_t)pk * C_);
      fb0 = *(const float4*)(fp + (size_t)pk * C_ + 64);
      FMA64(wa1, wb1, fa1, fb1)
    }
#undef FMA64
#undef FMA8
  }
  // combine the 4 q-partials (lane bits 4,5); all lanes end with full sums
#define RED2(v) { v += __shfl_xor(v, 16); v += __shfl_xor(v, 32); }
  #pragma unroll
  for (int r = 0; r < 8; ++r) {
    RED2(aL[r].x) RED2(aL[r].y) RED2(aL[r].z) RED2(aL[r].w)
    RED2(aH[r].x) RED2(aH[r].y) RED2(aH[r].z) RED2(aH[r].w)
  }
#undef RED2
  // q-group g writes rows {2g, 2g+1}: 16 lanes x float4 = 256 B contiguous per store
  #pragma unroll
  for (int r = 0; r < 8; ++r) {
    if ((r >> 1) == q) {
      float* pt = part + (size_t)ks * (B_ * L_ * C_)
                + ((size_t)b * L_ + l0 + w8 + r) * C_;
      *(float4*)(pt + c0)      = aL[r];
      *(float4*)(pt + c0 + 64) = aH[r];
    }
  }
}

// gf = pairwise-tree sum of NS part slices (float4, 131072 groups)
template<int NS>
__global__ __launch_bounds__(256) void k_red(const float* __restrict__ part,
                                             float* __restrict__ gf) {
  int t = blockIdx.x * 256 + threadIdx.x;        // 131072
  const float4* p = (const float4*)part;
  float4 s[NS];
  #pragma unroll
  for (int i = 0; i < NS; ++i) s[i] = p[t + (size_t)i * 131072];
  #pragma unroll
  for (int stride = 1; stride < NS; stride <<= 1)
    #pragma unroll
    for (int i = 0; i + stride < NS; i += 2 * stride) {
      s[i].x += s[i + stride].x; s[i].y += s[i + stride].y;
      s[i].z += s[i + stride].z; s[i].w += s[i + stride].w;
    }
  ((float4*)gf)[t] = s[0];
}

extern "C" void kernel_launch(void* const* d_in, const int* in_sizes, int n_in,
                              void* d_out, int out_size, void* d_ws, size_t ws_size,
                              hipStream_t stream) {
  const float* bbox  = (const float*)d_in[0];
  const float* locs  = (const float*)d_in[1];
  const float* feats = (const float*)d_in[2];
  const float* over  = (const float*)d_in[3];
  const float* rays  = (const float*)d_in[4];
  const float* w1    = (const float*)d_in[5];
  const float* b1    = (const float*)d_in[6];
  const float* w2    = (const float*)d_in[7];
  const float* b2    = (const float*)d_in[8];
  const float* fw    = (const float*)d_in[9];
  const float* fb    = (const float*)d_in[10];

  float* ws     = (float*)d_ws;
  int*   ind    = (int*)ws;
  float* Kscal  = ws + 81920;
  float* Rc     = ws + 163840;
  float* Pc     = ws + 256000;
  float* pano   = ws + 276480;
  float* ovmax  = ws + 317440;
  float* ovmean = ws + 321536;
  float* Ft     = ws + 325632;
  float* part   = ws + 2947072;

  float* gf   = (float*)d_out;
  float* attn = gf + (B_ * L_ * C_);             // 20.97M floats

  k_fa  <<<456, 256, 0, stream>>>(feats, over, rays, w1, w2, fw,
                                  pano, ovmax, ovmean, Rc);
  k_fb  <<<720, 256, 0, stream>>>(pano, bbox, locs, ovmax, ovmean, feats,
                                  w1, w2, b1, b2, fw, fb, Pc, ind, Kscal, Ft);
  k_soft<<<4096, 256, 0, stream>>>(Rc, Pc, Kscal, ind, attn);

  // 8-way ksplit needs part = 8*524288 floats; use it only if the workspace fits.
  if (ws_size / 4 >= (size_t)(2947072 + 8 * 524288)) {
    k_mm<3><<<1024, 256, 0, stream>>>(attn, Ft, part);
    k_red<8><<<512, 256, 0, stream>>>(part, gf);
  } else {
    k_mm<2><<<512, 256, 0, stream>>>(attn, Ft, part);
    k_red<4><<<512, 256, 0, stream>>>(part, gf);
  }
}

// Round 8
// 214.313 us; speedup vs baseline: 1.1243x; 1.1243x over previous
//
#include <hip/hip_runtime.h>

#define B_  4
#define NN_ 20
#define C_  128
#define H_  8
#define W_  32
#define P_  256      // H*W
#define GS_ 32
#define L_  1024     // GS*GS
#define K_  5120     // NN*P

// ---------------- ws layout (float elements) ----------------
// ind   : int   [B*L*NN]   @ 0         (81920)
// Kscal : float [B*L*NN]   @ 81920     (81920)
// Rc    : float [360*P]    @ 163840    (92160)
// Pc    : float [B*NN*P]   @ 256000    (20480)
// (pano/ovmax/ovmean slots retired: ov terms are per-(b,l) constants -> cancel
//  in softmax; pano stats recomputed inline in the pano-conv block)
// Ft    : float [B*K*C]    @ 325632    (2621440)
// part  : float [NS*B*L*C] @ 2947072   (NS*524288); NS=8 if ws fits, else 4

// ---- single fused front-end:
//   bid   0..359 : rays conv -> Rc
//   bid 360..439 : pano stats (inline from feats) + pano conv -> Pc
//   bid 440..759 : geo (ray index + D-only scalar logit term) -> ind, Kscal
//   bid 760..1079: feats transpose -> Ft
// geo note: the overhead-feature logit terms depend only on (b,l) — constant
// across the softmax axis (n,p) — so softmax is invariant to them; dropped.
__global__ __launch_bounds__(256) void k_front(const float* __restrict__ feats,
                                               const float* __restrict__ rays,
                                               const float* __restrict__ bbox,
                                               const float* __restrict__ locs,
                                               const float* __restrict__ w1,
                                               const float* __restrict__ w2,
                                               const float* __restrict__ b1,
                                               const float* __restrict__ b2,
                                               const float* __restrict__ fw,
                                               const float* __restrict__ fb,
                                               float* __restrict__ Rc,
                                               float* __restrict__ Pc,
                                               int* __restrict__ ind,
                                               float* __restrict__ Kscal,
                                               float* __restrict__ Ft) {
  __shared__ float s[32 * 257];
  int bid = blockIdx.x, tid = threadIdx.x;
  if (bid < 360) {
    int a = bid;                                 // 360 angles
    #pragma unroll
    for (int c = 0; c < 3; ++c) s[c * P_ + tid] = rays[(a * 3 + c) * P_ + tid];
    __syncthreads();
    int y = tid >> 5, x = tid & 31;
    float acc1 = 0.f, acc2 = 0.f;
    #pragma unroll
    for (int c = 0; c < 3; ++c) {
      const float* sc  = s + c * P_;
      const float* w1c = w1 + (1 + c) * 9;
      const float* w2c = w2 + (1 + c) * 25;
      #pragma unroll
      for (int dy = 0; dy < 3; ++dy) { int yy = ((y + dy + 7) & 7) * 32;
        #pragma unroll
        for (int dx = 0; dx < 3; ++dx) { int xx = (x + dx + 31) & 31;
          acc1 += sc[yy + xx] * w1c[dy * 3 + dx]; } }
      #pragma unroll
      for (int dy = 0; dy < 5; ++dy) { int yy = ((y + dy + 6) & 7) * 32;
        #pragma unroll
        for (int dx = 0; dx < 5; ++dx) { int xx = (x + dx + 30) & 31;
          acc2 += sc[yy + xx] * w2c[dy * 5 + dx]; } }
    }
    Rc[a * P_ + tid] = fw[0] * acc1 + fw[1] * acc2;
  } else if (bid < 440) {
    int bn = bid - 360;                          // b*NN + n
    // inline pano stats: max/mean over 128 channels at this pixel
    const float* src = feats + bn * C_ * P_ + tid;
    float mx = -3.4e38f, sm = 0.f;
    #pragma unroll 8
    for (int c = 0; c < C_; ++c) { float v = src[c * P_]; mx = fmaxf(mx, v); sm += v; }
    s[tid]      = mx;
    s[P_ + tid] = sm * (1.0f / 128.0f);
    __syncthreads();
    int y = tid >> 5, x = tid & 31;
    float acc1 = 0.f, acc2 = 0.f;
    #pragma unroll
    for (int c = 0; c < 2; ++c) {
      const float* sc  = s + c * P_;
      const float* w1c = w1 + (4 + c) * 9;
      const float* w2c = w2 + (4 + c) * 25;
      #pragma unroll
      for (int dy = 0; dy < 3; ++dy) { int yy = ((y + dy + 7) & 7) * 32;
        #pragma unroll
        for (int dx = 0; dx < 3; ++dx) { int xx = (x + dx + 31) & 31;
          acc1 += sc[yy + xx] * w1c[dy * 3 + dx]; } }
      #pragma unroll
      for (int dy = 0; dy < 5; ++dy) { int yy = ((y + dy + 6) & 7) * 32;
        #pragma unroll
        for (int dx = 0; dx < 5; ++dx) { int xx = (x + dx + 30) & 31;
          acc2 += sc[yy + xx] * w2c[dy * 5 + dx]; } }
    }
    Pc[bn * P_ + tid] = fw[0] * acc1 + fw[1] * acc2;
  } else if (bid < 760) {
    int t = (bid - 440) * 256 + tid;             // B*L*NN = 81920
    int n = t % NN_;
    int r = t / NN_;                             // b*L + l
    int l = r & 1023, b = r >> 10;
    int i = l >> 5, j = l & 31;
    float y0 = bbox[b * 4 + 0], x0 = bbox[b * 4 + 1];
    float y1 = bbox[b * 4 + 2], x1 = bbox[b * 4 + 3];
    float gy = (i == 31) ? y1 : (y0 + ((y1 - y0) / 31.0f) * (float)i);
    float gx = (j == 31) ? x1 : (x0 + ((x1 - x0) / 31.0f) * (float)j);
    float d0 = gy - locs[(b * NN_ + n) * 2 + 0];
    float d1 = gx - locs[(b * NN_ + n) * 2 + 1];
    float D  = sqrtf(d0 * d0 + d1 * d1 + 1e-12f);
    float th = atan2f(d1, d0);
    if (th < 0.f) th += 6.283185307179586f;
    float deg = th * 57.29577951308232f;
    int di = (int)rintf(deg);
    if (di >= 360) di -= 360;
    float s10 = 0.f, s20 = 0.f;
    #pragma unroll
    for (int q = 0; q < 9; ++q) s10 += w1[q];
    #pragma unroll
    for (int q = 0; q < 25; ++q) s20 += w2[q];
    ind[t]   = di;
    Kscal[t] = fw[0] * (D * s10 + b1[0]) + fw[1] * (D * s20 + b2[0]) + fb[0];
  } else {
    int bb = bid - 760;                          // 320 = (b*NN+n)*4 + c-quarter
    int bn = bb >> 2, cq = bb & 3;
    int b = bn / NN_, n = bn % NN_;
    int c0 = cq * 32;
    #pragma unroll 4
    for (int cc = 0; cc < 32; ++cc)
      s[cc * 257 + tid] = feats[(bn * C_ + c0 + cc) * P_ + tid];
    __syncthreads();
    int c = tid & 31, p8 = tid >> 5;
    #pragma unroll 4
    for (int pp = 0; pp < 32; ++pp) {
      int p = pp * 8 + p8;
      Ft[((size_t)b * K_ + n * P_ + p) * C_ + c0 + c] = s[c * 257 + p];
    }
  }
}

// Per grid cell: assemble logits, softmax over (n,p)=5120, write fp32 attn.
__global__ __launch_bounds__(256) void k_soft(const float* __restrict__ Rc,
                                              const float* __restrict__ Pc,
                                              const float* __restrict__ Kscal,
                                              const int* __restrict__ ind,
                                              float* __restrict__ attn) {
  int bl = blockIdx.x;                           // b*L + l
  int b = bl >> 10;
  int tid = threadIdx.x;                         // pixel p
  __shared__ float sK[NN_];
  __shared__ int   sI[NN_];
  __shared__ float red[8];                       // [0..3]=max, [4..7]=sum
  if (tid < NN_) { sI[tid] = ind[bl * NN_ + tid]; sK[tid] = Kscal[bl * NN_ + tid]; }
  __syncthreads();
  float lg[NN_];
  #pragma unroll
  for (int n = 0; n < NN_; ++n)
    lg[n] = Rc[sI[n] * P_ + tid] + Pc[(b * NN_ + n) * P_ + tid] + sK[n];
  float m = -3.4e38f;
  #pragma unroll
  for (int n = 0; n < NN_; ++n) m = fmaxf(m, lg[n]);
  #pragma unroll
  for (int off = 32; off > 0; off >>= 1) m = fmaxf(m, __shfl_xor(m, off));
  if ((tid & 63) == 0) red[tid >> 6] = m;
  __syncthreads();
  m = fmaxf(fmaxf(red[0], red[1]), fmaxf(red[2], red[3]));
  float ssum = 0.f;
  #pragma unroll
  for (int n = 0; n < NN_; ++n) { lg[n] = expf(lg[n] - m); ssum += lg[n]; }
  #pragma unroll
  for (int off = 32; off > 0; off >>= 1) ssum += __shfl_xor(ssum, off);
  if ((tid & 63) == 0) red[4 + (tid >> 6)] = ssum;
  __syncthreads();
  float inv = 1.0f / ((red[4] + red[5]) + (red[6] + red[7]));
  #pragma unroll
  for (int n = 0; n < NN_; ++n)
    attn[((size_t)bl * NN_ + n) * P_ + tid] = lg[n] * inv;
}

// part[ks][b,l,c] = sum_{k in split ks} attn[b,l,k] * Ft[b,k,c]
// Grid = 4b x 32lt x NS; 256 thr = 4 waves; tile 32 l x 128 c x (K/NS) k.
// Wave w owns l = l0+8w..+7. Lane = (q = lane>>4 k-offset, cg = lane&15 -> c).
// 2-stage pipeline on the GLOBAL Ft loads only (long-latency): step i+1's
// 2 dwordx4 issue before step i's 64 FMAs. Weights (LDS, short-latency) JIT.
// PLAIN launch_bounds(256): r7's (256,4) hint forced VGPR=64 -> scratch spill
// (WRITE_SIZE 128MB). Budget here: 64 acc + 16 pipe + 8 w + addr ~ 105 VGPR.
// Accumulation order identical to r4/r6 -> bitwise-identical output.
template<int NSH>
__global__ __launch_bounds__(256) void k_mm(const float* __restrict__ attn,
                                            const float* __restrict__ Ft,
                                            float* __restrict__ part) {
  constexpr int NS = 1 << NSH;
  constexpr int KC = K_ / NS;                    // k per block
  __shared__ __align__(16) float sW[128 * 36];   // sW[k][l], stride 36: b128 align
  int bid = blockIdx.x;
  int ks = bid & (NS - 1);
  int lt = (bid >> NSH) & 31;
  int b  = bid >> (NSH + 5);
  int l0 = lt << 5;                              // 32 l per block
  int kbase = ks * KC;
  int tid = threadIdx.x;
  int w8 = (tid >> 6) << 3;                      // wave * 8 -> l offset
  int lane = tid & 63;
  int q  = lane >> 4;                            // 0..3 : k offset within 4-k step
  int c0 = (lane & 15) << 2;                     // c 0..60 (lo half), +64 (hi half)
  int kst = tid & 127, hst = tid >> 7;           // staging role: k, l-half
  float4 aL[8], aH[8];
  #pragma unroll
  for (int r = 0; r < 8; ++r) {
    aL[r] = make_float4(0.f, 0.f, 0.f, 0.f);
    aH[r] = make_float4(0.f, 0.f, 0.f, 0.f);
  }
  const float* arow  = attn + ((size_t)b * L_ + l0) * K_ + kbase;
  const float* fbase = Ft + ((size_t)b * K_ + kbase + q) * C_ + c0;
  for (int kc0 = 0; kc0 < KC; kc0 += 128) {
    __syncthreads();                             // all waves done reading sW
    #pragma unroll
    for (int r = 0; r < 16; ++r)                 // 128 k x 32 l, 16 elems/thread
      sW[kst * 36 + hst * 16 + r] = arow[(size_t)(hst * 16 + r) * K_ + kc0 + kst];
    __syncthreads();
    const float* fp  = fbase + (size_t)kc0 * C_;
    const float* swk = sW + q * 36 + w8;
#define FMA8(r, wgt, f0, f1) \
    aL[r].x += (wgt) * f0.x; aL[r].y += (wgt) * f0.y; \
    aL[r].z += (wgt) * f0.z; aL[r].w += (wgt) * f0.w; \
    aH[r].x += (wgt) * f1.x; aH[r].y += (wgt) * f1.y; \
    aH[r].z += (wgt) * f1.z; aH[r].w += (wgt) * f1.w;
#define FMA64(wa, wb, f0, f1) \
    FMA8(0, wa.x, f0, f1) FMA8(1, wa.y, f0, f1) FMA8(2, wa.z, f0, f1) \
    FMA8(3, wa.w, f0, f1) FMA8(4, wb.x, f0, f1) FMA8(5, wb.y, f0, f1) \
    FMA8(6, wb.z, f0, f1) FMA8(7, wb.w, f0, f1)
    float4 fa0 = *(const float4*)(fp);
    float4 fb0 = *(const float4*)(fp + 64);
    #pragma unroll
    for (int kk = 0; kk < 128; kk += 8) {
      float4 fa1 = *(const float4*)(fp + (size_t)(kk + 4) * C_);
      float4 fb1 = *(const float4*)(fp + (size_t)(kk + 4) * C_ + 64);
      float4 wa  = *(const float4*)(swk + kk * 36);
      float4 wb  = *(const float4*)(swk + kk * 36 + 4);
      FMA64(wa, wb, fa0, fb0)
      int pk = (kk + 8 < 128) ? (kk + 8) : 0;    // folds at compile time
      fa0 = *(const float4*)(fp + (size_t)pk * C_);
      fb0 = *(const float4*)(fp + (size_t)pk * C_ + 64);
      wa  = *(const float4*)(swk + (kk + 4) * 36);
      wb  = *(const float4*)(swk + (kk + 4) * 36 + 4);
      FMA64(wa, wb, fa1, fb1)
    }
#undef FMA64
#undef FMA8
  }
  // combine the 4 q-partials (lane bits 4,5); all lanes end with full sums
#define RED2(v) { v += __shfl_xor(v, 16); v += __shfl_xor(v, 32); }
  #pragma unroll
  for (int r = 0; r < 8; ++r) {
    RED2(aL[r].x) RED2(aL[r].y) RED2(aL[r].z) RED2(aL[r].w)
    RED2(aH[r].x) RED2(aH[r].y) RED2(aH[r].z) RED2(aH[r].w)
  }
#undef RED2
  // q-group g writes rows {2g, 2g+1}: 16 lanes x float4 = 256 B contiguous per store
  #pragma unroll
  for (int r = 0; r < 8; ++r) {
    if ((r >> 1) == q) {
      float* pt = part + (size_t)ks * (B_ * L_ * C_)
                + ((size_t)b * L_ + l0 + w8 + r) * C_;
      *(float4*)(pt + c0)      = aL[r];
      *(float4*)(pt + c0 + 64) = aH[r];
    }
  }
}

// gf = pairwise-tree sum of NS part slices (float4, 131072 groups)
template<int NS>
__global__ __launch_bounds__(256) void k_red(const float* __restrict__ part,
                                             float* __restrict__ gf) {
  int t = blockIdx.x * 256 + threadIdx.x;        // 131072
  const float4* p = (const float4*)part;
  float4 s[NS];
  #pragma unroll
  for (int i = 0; i < NS; ++i) s[i] = p[t + (size_t)i * 131072];
  #pragma unroll
  for (int stride = 1; stride < NS; stride <<= 1)
    #pragma unroll
    for (int i = 0; i + stride < NS; i += 2 * stride) {
      s[i].x += s[i + stride].x; s[i].y += s[i + stride].y;
      s[i].z += s[i + stride].z; s[i].w += s[i + stride].w;
    }
  ((float4*)gf)[t] = s[0];
}

extern "C" void kernel_launch(void* const* d_in, const int* in_sizes, int n_in,
                              void* d_out, int out_size, void* d_ws, size_t ws_size,
                              hipStream_t stream) {
  const float* bbox  = (const float*)d_in[0];
  const float* locs  = (const float*)d_in[1];
  const float* feats = (const float*)d_in[2];
  const float* rays  = (const float*)d_in[4];
  const float* w1    = (const float*)d_in[5];
  const float* b1    = (const float*)d_in[6];
  const float* w2    = (const float*)d_in[7];
  const float* b2    = (const float*)d_in[8];
  const float* fw    = (const float*)d_in[9];
  const float* fb    = (const float*)d_in[10];

  float* ws     = (float*)d_ws;
  int*   ind    = (int*)ws;
  float* Kscal  = ws + 81920;
  float* Rc     = ws + 163840;
  float* Pc     = ws + 256000;
  float* Ft     = ws + 325632;
  float* part   = ws + 2947072;

  float* gf   = (float*)d_out;
  float* attn = gf + (B_ * L_ * C_);             // 20.97M floats

  k_front<<<1080, 256, 0, stream>>>(feats, rays, bbox, locs, w1, w2, b1, b2,
                                    fw, fb, Rc, Pc, ind, Kscal, Ft);
  k_soft<<<4096, 256, 0, stream>>>(Rc, Pc, Kscal, ind, attn);

  // 8-way ksplit needs part = 8*524288 floats; use it only if the workspace fits.
  if (ws_size / 4 >= (size_t)(2947072 + 8 * 524288)) {
    k_mm<3><<<1024, 256, 0, stream>>>(attn, Ft, part);
    k_red<8><<<512, 256, 0, stream>>>(part, gf);
  } else {
    k_mm<2><<<512, 256, 0, stream>>>(attn, Ft, part);
    k_red<4><<<512, 256, 0, stream>>>(part, gf);
  }
}

// Round 9
// 172.401 us; speedup vs baseline: 1.3976x; 1.2431x over previous
//
#include <hip/hip_runtime.h>

#define B_  4
#define NN_ 20
#define C_  128
#define H_  8
#define W_  32
#define P_  256      // H*W
#define GS_ 32
#define L_  1024     // GS*GS
#define K_  5120     // NN*P

// ---------------- ws layout (float elements) ----------------
// ind   : int   [B*L*NN]     @ 0        (81920)
// Kscal : float [B*L*NN]     @ 81920    (81920)
// Rc    : float [360*P]      @ 163840   (92160)
// Pc    : float [B*NN*P]     @ 256000   (20480)
// ePc   : float [B*NN*P]     @ 276480   (20480)   exp(Pc)
// Ft    : float [B*K*C]      @ 325632   (2621440)
// G     : float [B*360*NN*C] @ 2947072  (3686400)
// eRc   : float [360*P]      @ 6633472  (92160)   exp(Rc)
// total 6725632 floats = 26.9 MB; ws capacity >= 28.56 MB proven (r6 NS=8 ran)

// ---- single fused front-end (r8 structure + eRc/ePc side-writes):
//   bid   0..359 : rays conv -> Rc, eRc=exp(Rc)
//   bid 360..439 : pano stats (inline) + pano conv -> Pc, ePc=exp(Pc)
//   bid 440..759 : geo -> ind, Kscal (ov terms dropped: softmax-shift-invariant)
//   bid 760..1079: feats transpose -> Ft
__global__ __launch_bounds__(256) void k_front(const float* __restrict__ feats,
                                               const float* __restrict__ rays,
                                               const float* __restrict__ bbox,
                                               const float* __restrict__ locs,
                                               const float* __restrict__ w1,
                                               const float* __restrict__ w2,
                                               const float* __restrict__ b1,
                                               const float* __restrict__ b2,
                                               const float* __restrict__ fw,
                                               const float* __restrict__ fb,
                                               float* __restrict__ Rc,
                                               float* __restrict__ eRc,
                                               float* __restrict__ Pc,
                                               float* __restrict__ ePc,
                                               int* __restrict__ ind,
                                               float* __restrict__ Kscal,
                                               float* __restrict__ Ft) {
  __shared__ float s[32 * 257];
  int bid = blockIdx.x, tid = threadIdx.x;
  if (bid < 360) {
    int a = bid;                                 // 360 angles
    #pragma unroll
    for (int c = 0; c < 3; ++c) s[c * P_ + tid] = rays[(a * 3 + c) * P_ + tid];
    __syncthreads();
    int y = tid >> 5, x = tid & 31;
    float acc1 = 0.f, acc2 = 0.f;
    #pragma unroll
    for (int c = 0; c < 3; ++c) {
      const float* sc  = s + c * P_;
      const float* w1c = w1 + (1 + c) * 9;
      const float* w2c = w2 + (1 + c) * 25;
      #pragma unroll
      for (int dy = 0; dy < 3; ++dy) { int yy = ((y + dy + 7) & 7) * 32;
        #pragma unroll
        for (int dx = 0; dx < 3; ++dx) { int xx = (x + dx + 31) & 31;
          acc1 += sc[yy + xx] * w1c[dy * 3 + dx]; } }
      #pragma unroll
      for (int dy = 0; dy < 5; ++dy) { int yy = ((y + dy + 6) & 7) * 32;
        #pragma unroll
        for (int dx = 0; dx < 5; ++dx) { int xx = (x + dx + 30) & 31;
          acc2 += sc[yy + xx] * w2c[dy * 5 + dx]; } }
    }
    float v = fw[0] * acc1 + fw[1] * acc2;
    Rc[a * P_ + tid]  = v;
    eRc[a * P_ + tid] = expf(v);
  } else if (bid < 440) {
    int bn = bid - 360;                          // b*NN + n
    const float* src = feats + bn * C_ * P_ + tid;
    float mx = -3.4e38f, sm = 0.f;
    #pragma unroll 8
    for (int c = 0; c < C_; ++c) { float v = src[c * P_]; mx = fmaxf(mx, v); sm += v; }
    s[tid]      = mx;
    s[P_ + tid] = sm * (1.0f / 128.0f);
    __syncthreads();
    int y = tid >> 5, x = tid & 31;
    float acc1 = 0.f, acc2 = 0.f;
    #pragma unroll
    for (int c = 0; c < 2; ++c) {
      const float* sc  = s + c * P_;
      const float* w1c = w1 + (4 + c) * 9;
      const float* w2c = w2 + (4 + c) * 25;
      #pragma unroll
      for (int dy = 0; dy < 3; ++dy) { int yy = ((y + dy + 7) & 7) * 32;
        #pragma unroll
        for (int dx = 0; dx < 3; ++dx) { int xx = (x + dx + 31) & 31;
          acc1 += sc[yy + xx] * w1c[dy * 3 + dx]; } }
      #pragma unroll
      for (int dy = 0; dy < 5; ++dy) { int yy = ((y + dy + 6) & 7) * 32;
        #pragma unroll
        for (int dx = 0; dx < 5; ++dx) { int xx = (x + dx + 30) & 31;
          acc2 += sc[yy + xx] * w2c[dy * 5 + dx]; } }
    }
    float v = fw[0] * acc1 + fw[1] * acc2;
    Pc[bn * P_ + tid]  = v;
    ePc[bn * P_ + tid] = expf(v);
  } else if (bid < 760) {
    int t = (bid - 440) * 256 + tid;             // B*L*NN = 81920
    int n = t % NN_;
    int r = t / NN_;                             // b*L + l
    int l = r & 1023, b = r >> 10;
    int i = l >> 5, j = l & 31;
    float y0 = bbox[b * 4 + 0], x0 = bbox[b * 4 + 1];
    float y1 = bbox[b * 4 + 2], x1 = bbox[b * 4 + 3];
    float gy = (i == 31) ? y1 : (y0 + ((y1 - y0) / 31.0f) * (float)i);
    float gx = (j == 31) ? x1 : (x0 + ((x1 - x0) / 31.0f) * (float)j);
    float d0 = gy - locs[(b * NN_ + n) * 2 + 0];
    float d1 = gx - locs[(b * NN_ + n) * 2 + 1];
    float D  = sqrtf(d0 * d0 + d1 * d1 + 1e-12f);
    float th = atan2f(d1, d0);
    if (th < 0.f) th += 6.283185307179586f;
    float deg = th * 57.29577951308232f;
    int di = (int)rintf(deg);
    if (di >= 360) di -= 360;
    float s10 = 0.f, s20 = 0.f;
    #pragma unroll
    for (int q = 0; q < 9; ++q) s10 += w1[q];
    #pragma unroll
    for (int q = 0; q < 25; ++q) s20 += w2[q];
    ind[t]   = di;
    Kscal[t] = fw[0] * (D * s10 + b1[0]) + fw[1] * (D * s20 + b2[0]) + fb[0];
  } else {
    int bb = bid - 760;                          // 320 = (b*NN+n)*4 + c-quarter
    int bn = bb >> 2, cq = bb & 3;
    int b = bn / NN_, n = bn % NN_;
    int c0 = cq * 32;
    #pragma unroll 4
    for (int cc = 0; cc < 32; ++cc)
      s[cc * 257 + tid] = feats[(bn * C_ + c0 + cc) * P_ + tid];
    __syncthreads();
    int c = tid & 31, p8 = tid >> 5;
    #pragma unroll 4
    for (int pp = 0; pp < 32; ++pp) {
      int p = pp * 8 + p8;
      Ft[((size_t)b * K_ + n * P_ + p) * C_ + c0 + c] = s[c * 257 + p];
    }
  }
}

// G[b,a,n,c] = sum_p eRc[a,p] * ePc[b,n,p] * Ft[b,(n,p),c]
// Clone of the r8-proven k_mm structure: out-tile 32a x 128c, K=256p in 2
// chunks of 128, 4 waves, q = lane>>4 p-parity split, 2-stage Ft pipeline.
// The ePc[n,p] factor is folded into sW staging (one mult per staged elem).
// Grid 960 = 4b x 20n x 12at; at=11 covers a 352..383: staging rows clamped
// to 359 (in-bounds, values unused), stores guarded by a<360.
__global__ __launch_bounds__(256) void k_G(const float* __restrict__ eRc,
                                           const float* __restrict__ ePc,
                                           const float* __restrict__ Ft,
                                           float* __restrict__ G) {
  __shared__ __align__(16) float sW[128 * 36];   // sW[p][a], stride 36: b128 align
  int bid = blockIdx.x;
  int at = bid % 12;
  int n  = (bid / 12) % NN_;
  int b  = bid / 240;
  int a0 = at << 5;                              // 32 a per block
  int tid = threadIdx.x;
  int w8 = (tid >> 6) << 3;                      // wave * 8 -> a offset
  int lane = tid & 63;
  int q  = lane >> 4;                            // 0..3 : p offset within 4-p step
  int c0 = (lane & 15) << 2;                     // c 0..60 (lo half), +64 (hi half)
  int kst = tid & 127, hst = tid >> 7;           // staging role: p, a-half
  float4 aL[8], aH[8];
  #pragma unroll
  for (int r = 0; r < 8; ++r) {
    aL[r] = make_float4(0.f, 0.f, 0.f, 0.f);
    aH[r] = make_float4(0.f, 0.f, 0.f, 0.f);
  }
  const float* epc   = ePc + (b * NN_ + n) * P_;
  const float* fbase = Ft + ((size_t)(b * NN_ + n) * P_ + q) * C_ + c0;
  for (int pc0 = 0; pc0 < 256; pc0 += 128) {
    __syncthreads();                             // all waves done reading sW
    #pragma unroll
    for (int r = 0; r < 16; ++r) {               // 128 p x 32 a, 16 elems/thread
      int ar = a0 + hst * 16 + r;
      if (ar > 359) ar = 359;                    // clamp: in-bounds, unused rows
      sW[kst * 36 + hst * 16 + r] = eRc[ar * P_ + pc0 + kst] * epc[pc0 + kst];
    }
    __syncthreads();
    const float* fp  = fbase + (size_t)pc0 * C_;
    const float* swk = sW + q * 36 + w8;
#define FMA8(r, wgt, f0, f1) \
    aL[r].x += (wgt) * f0.x; aL[r].y += (wgt) * f0.y; \
    aL[r].z += (wgt) * f0.z; aL[r].w += (wgt) * f0.w; \
    aH[r].x += (wgt) * f1.x; aH[r].y += (wgt) * f1.y; \
    aH[r].z += (wgt) * f1.z; aH[r].w += (wgt) * f1.w;
#define FMA64(wa, wb, f0, f1) \
    FMA8(0, wa.x, f0, f1) FMA8(1, wa.y, f0, f1) FMA8(2, wa.z, f0, f1) \
    FMA8(3, wa.w, f0, f1) FMA8(4, wb.x, f0, f1) FMA8(5, wb.y, f0, f1) \
    FMA8(6, wb.z, f0, f1) FMA8(7, wb.w, f0, f1)
    float4 fa0 = *(const float4*)(fp);
    float4 fb0 = *(const float4*)(fp + 64);
    #pragma unroll
    for (int kk = 0; kk < 128; kk += 8) {
      float4 fa1 = *(const float4*)(fp + (size_t)(kk + 4) * C_);
      float4 fb1 = *(const float4*)(fp + (size_t)(kk + 4) * C_ + 64);
      float4 wa  = *(const float4*)(swk + kk * 36);
      float4 wb  = *(const float4*)(swk + kk * 36 + 4);
      FMA64(wa, wb, fa0, fb0)
      int pk = (kk + 8 < 128) ? (kk + 8) : 0;    // folds at compile time
      fa0 = *(const float4*)(fp + (size_t)pk * C_);
      fb0 = *(const float4*)(fp + (size_t)pk * C_ + 64);
      wa  = *(const float4*)(swk + (kk + 4) * 36);
      wb  = *(const float4*)(swk + (kk + 4) * 36 + 4);
      FMA64(wa, wb, fa1, fb1)
    }
#undef FMA64
#undef FMA8
  }
  // combine the 4 q-partials (lane bits 4,5)
#define RED2(v) { v += __shfl_xor(v, 16); v += __shfl_xor(v, 32); }
  #pragma unroll
  for (int r = 0; r < 8; ++r) {
    RED2(aL[r].x) RED2(aL[r].y) RED2(aL[r].z) RED2(aL[r].w)
    RED2(aH[r].x) RED2(aH[r].y) RED2(aH[r].z) RED2(aH[r].w)
  }
#undef RED2
  // q-group g writes a-rows {2g, 2g+1}
  #pragma unroll
  for (int r = 0; r < 8; ++r) {
    if ((r >> 1) == q) {
      int a = a0 + w8 + r;
      if (a < 360) {
        float* pt = G + (((size_t)b * 360 + a) * NN_ + n) * C_;
        *(float4*)(pt + c0)      = aL[r];
        *(float4*)(pt + c0 + 64) = aH[r];
      }
    }
  }
}

// Per grid cell: assemble logits, softmax over (n,p)=5120, write fp32 attn;
// then fused gf gather: gf[l,c] = sum_n exp(sK[n]-m)*inv * G[ind[n], n, c].
__global__ __launch_bounds__(256) void k_soft(const float* __restrict__ Rc,
                                              const float* __restrict__ Pc,
                                              const float* __restrict__ Kscal,
                                              const int* __restrict__ ind,
                                              const float* __restrict__ G,
                                              float* __restrict__ attn,
                                              float* __restrict__ gf) {
  int bl = blockIdx.x;                           // b*L + l
  int b = bl >> 10;
  int tid = threadIdx.x;                         // pixel p
  __shared__ float sK[NN_];
  __shared__ int   sI[NN_];
  __shared__ float red[8];                       // [0..3]=max, [4..7]=sum
  if (tid < NN_) { sI[tid] = ind[bl * NN_ + tid]; sK[tid] = Kscal[bl * NN_ + tid]; }
  __syncthreads();
  float lg[NN_];
  #pragma unroll
  for (int n = 0; n < NN_; ++n)
    lg[n] = Rc[sI[n] * P_ + tid] + Pc[(b * NN_ + n) * P_ + tid] + sK[n];
  float m = -3.4e38f;
  #pragma unroll
  for (int n = 0; n < NN_; ++n) m = fmaxf(m, lg[n]);
  #pragma unroll
  for (int off = 32; off > 0; off >>= 1) m = fmaxf(m, __shfl_xor(m, off));
  if ((tid & 63) == 0) red[tid >> 6] = m;
  __syncthreads();
  m = fmaxf(fmaxf(red[0], red[1]), fmaxf(red[2], red[3]));
  float ssum = 0.f;
  #pragma unroll
  for (int n = 0; n < NN_; ++n) { lg[n] = expf(lg[n] - m); ssum += lg[n]; }
  #pragma unroll
  for (int off = 32; off > 0; off >>= 1) ssum += __shfl_xor(ssum, off);
  if ((tid & 63) == 0) red[4 + (tid >> 6)] = ssum;
  __syncthreads();
  float inv = 1.0f / ((red[4] + red[5]) + (red[6] + red[7]));
  #pragma unroll
  for (int n = 0; n < NN_; ++n)
    attn[((size_t)bl * NN_ + n) * P_ + tid] = lg[n] * inv;
  // fused gather (G rows are L2/L3-resident: 3.7 MB per b)
  if (tid < C_) {
    float acc = 0.f;
    #pragma unroll
    for (int n = 0; n < NN_; ++n) {
      float wn = expf(sK[n] - m) * inv;
      acc += wn * G[(((size_t)b * 360 + sI[n]) * NN_ + n) * C_ + tid];
    }
    gf[(size_t)bl * C_ + tid] = acc;
  }
}

extern "C" void kernel_launch(void* const* d_in, const int* in_sizes, int n_in,
                              void* d_out, int out_size, void* d_ws, size_t ws_size,
                              hipStream_t stream) {
  const float* bbox  = (const float*)d_in[0];
  const float* locs  = (const float*)d_in[1];
  const float* feats = (const float*)d_in[2];
  const float* rays  = (const float*)d_in[4];
  const float* w1    = (const float*)d_in[5];
  const float* b1    = (const float*)d_in[6];
  const float* w2    = (const float*)d_in[7];
  const float* b2    = (const float*)d_in[8];
  const float* fw    = (const float*)d_in[9];
  const float* fb    = (const float*)d_in[10];

  float* ws     = (float*)d_ws;
  int*   ind    = (int*)ws;
  float* Kscal  = ws + 81920;
  float* Rc     = ws + 163840;
  float* Pc     = ws + 256000;
  float* ePc    = ws + 276480;
  float* Ft     = ws + 325632;
  float* G      = ws + 2947072;
  float* eRc    = ws + 6633472;

  float* gf   = (float*)d_out;
  float* attn = gf + (B_ * L_ * C_);             // 20.97M floats

  k_front<<<1080, 256, 0, stream>>>(feats, rays, bbox, locs, w1, w2, b1, b2,
                                    fw, fb, Rc, eRc, Pc, ePc, ind, Kscal, Ft);
  k_G    <<<960, 256, 0, stream>>>(eRc, ePc, Ft, G);
  k_soft <<<4096, 256, 0, stream>>>(Rc, Pc, Kscal, ind, G, attn, gf);
}

// Round 10
// 167.252 us; speedup vs baseline: 1.4406x; 1.0308x over previous
//
#include <hip/hip_runtime.h>

#define B_  4
#define NN_ 20
#define C_  128
#define H_  8
#define W_  32
#define P_  256      // H*W
#define GS_ 32
#define L_  1024     // GS*GS
#define K_  5120     // NN*P

// ---------------- ws layout (float elements) ----------------
// ind   : int   [B*L*NN]     @ 0        (81920)
// Kscal : float [B*L*NN]     @ 81920    (81920)
// eRc   : float [360*P]      @ 163840   (92160)   exp(rays-conv)
// ePc   : float [B*NN*P]     @ 256000   (20480)   exp(pano-conv)
// S     : float [B*360*NN]   @ 276480   (28800)   sum_p eRc*ePc
// Ft    : float [B*K*C]      @ 325632   (2621440)
// G     : float [B*360*NN*C] @ 2947072  (3686400)
// total 6633472 floats = 26.5 MB; capacity >= 28.56 MB proven (r6 NS=8 ran)

// ---- single fused front-end:
//   bid   0..359 : rays conv -> eRc = exp(conv)
//   bid 360..439 : pano stats (inline) + pano conv -> ePc = exp(conv)
//   bid 440..759 : geo -> ind, Kscal (ov terms dropped: softmax-shift-invariant)
//   bid 760..1079: feats transpose -> Ft
__global__ __launch_bounds__(256) void k_front(const float* __restrict__ feats,
                                               const float* __restrict__ rays,
                                               const float* __restrict__ bbox,
                                               const float* __restrict__ locs,
                                               const float* __restrict__ w1,
                                               const float* __restrict__ w2,
                                               const float* __restrict__ b1,
                                               const float* __restrict__ b2,
                                               const float* __restrict__ fw,
                                               const float* __restrict__ fb,
                                               float* __restrict__ eRc,
                                               float* __restrict__ ePc,
                                               int* __restrict__ ind,
                                               float* __restrict__ Kscal,
                                               float* __restrict__ Ft) {
  __shared__ float s[32 * 257];
  int bid = blockIdx.x, tid = threadIdx.x;
  if (bid < 360) {
    int a = bid;                                 // 360 angles
    #pragma unroll
    for (int c = 0; c < 3; ++c) s[c * P_ + tid] = rays[(a * 3 + c) * P_ + tid];
    __syncthreads();
    int y = tid >> 5, x = tid & 31;
    float acc1 = 0.f, acc2 = 0.f;
    #pragma unroll
    for (int c = 0; c < 3; ++c) {
      const float* sc  = s + c * P_;
      const float* w1c = w1 + (1 + c) * 9;
      const float* w2c = w2 + (1 + c) * 25;
      #pragma unroll
      for (int dy = 0; dy < 3; ++dy) { int yy = ((y + dy + 7) & 7) * 32;
        #pragma unroll
        for (int dx = 0; dx < 3; ++dx) { int xx = (x + dx + 31) & 31;
          acc1 += sc[yy + xx] * w1c[dy * 3 + dx]; } }
      #pragma unroll
      for (int dy = 0; dy < 5; ++dy) { int yy = ((y + dy + 6) & 7) * 32;
        #pragma unroll
        for (int dx = 0; dx < 5; ++dx) { int xx = (x + dx + 30) & 31;
          acc2 += sc[yy + xx] * w2c[dy * 5 + dx]; } }
    }
    eRc[a * P_ + tid] = expf(fw[0] * acc1 + fw[1] * acc2);
  } else if (bid < 440) {
    int bn = bid - 360;                          // b*NN + n
    const float* src = feats + bn * C_ * P_ + tid;
    float mx = -3.4e38f, sm = 0.f;
    #pragma unroll 8
    for (int c = 0; c < C_; ++c) { float v = src[c * P_]; mx = fmaxf(mx, v); sm += v; }
    s[tid]      = mx;
    s[P_ + tid] = sm * (1.0f / 128.0f);
    __syncthreads();
    int y = tid >> 5, x = tid & 31;
    float acc1 = 0.f, acc2 = 0.f;
    #pragma unroll
    for (int c = 0; c < 2; ++c) {
      const float* sc  = s + c * P_;
      const float* w1c = w1 + (4 + c) * 9;
      const float* w2c = w2 + (4 + c) * 25;
      #pragma unroll
      for (int dy = 0; dy < 3; ++dy) { int yy = ((y + dy + 7) & 7) * 32;
        #pragma unroll
        for (int dx = 0; dx < 3; ++dx) { int xx = (x + dx + 31) & 31;
          acc1 += sc[yy + xx] * w1c[dy * 3 + dx]; } }
      #pragma unroll
      for (int dy = 0; dy < 5; ++dy) { int yy = ((y + dy + 6) & 7) * 32;
        #pragma unroll
        for (int dx = 0; dx < 5; ++dx) { int xx = (x + dx + 30) & 31;
          acc2 += sc[yy + xx] * w2c[dy * 5 + dx]; } }
    }
    ePc[bn * P_ + tid] = expf(fw[0] * acc1 + fw[1] * acc2);
  } else if (bid < 760) {
    int t = (bid - 440) * 256 + tid;             // B*L*NN = 81920
    int n = t % NN_;
    int r = t / NN_;                             // b*L + l
    int l = r & 1023, b = r >> 10;
    int i = l >> 5, j = l & 31;
    float y0 = bbox[b * 4 + 0], x0 = bbox[b * 4 + 1];
    float y1 = bbox[b * 4 + 2], x1 = bbox[b * 4 + 3];
    float gy = (i == 31) ? y1 : (y0 + ((y1 - y0) / 31.0f) * (float)i);
    float gx = (j == 31) ? x1 : (x0 + ((x1 - x0) / 31.0f) * (float)j);
    float d0 = gy - locs[(b * NN_ + n) * 2 + 0];
    float d1 = gx - locs[(b * NN_ + n) * 2 + 1];
    float D  = sqrtf(d0 * d0 + d1 * d1 + 1e-12f);
    float th = atan2f(d1, d0);
    if (th < 0.f) th += 6.283185307179586f;
    float deg = th * 57.29577951308232f;
    int di = (int)rintf(deg);
    if (di >= 360) di -= 360;
    float s10 = 0.f, s20 = 0.f;
    #pragma unroll
    for (int q = 0; q < 9; ++q) s10 += w1[q];
    #pragma unroll
    for (int q = 0; q < 25; ++q) s20 += w2[q];
    ind[t]   = di;
    Kscal[t] = fw[0] * (D * s10 + b1[0]) + fw[1] * (D * s20 + b2[0]) + fb[0];
  } else {
    int bb = bid - 760;                          // 320 = (b*NN+n)*4 + c-quarter
    int bn = bb >> 2, cq = bb & 3;
    int b = bn / NN_, n = bn % NN_;
    int c0 = cq * 32;
    #pragma unroll 4
    for (int cc = 0; cc < 32; ++cc)
      s[cc * 257 + tid] = feats[(bn * C_ + c0 + cc) * P_ + tid];
    __syncthreads();
    int c = tid & 31, p8 = tid >> 5;
    #pragma unroll 4
    for (int pp = 0; pp < 32; ++pp) {
      int p = pp * 8 + p8;
      Ft[((size_t)b * K_ + n * P_ + p) * C_ + c0 + c] = s[c * 257 + p];
    }
  }
}

// G[b,a,n,c] = sum_p eRc[a,p]*ePc[b,n,p]*Ft[b,(n,p),c]
// S[b,a,n]   = sum_p eRc[a,p]*ePc[b,n,p]   (softmax denominator table)
// r8-proven structure: 32a x 128c tile, 2 chunks of 128 p, 4 waves, q-split,
// 2-stage Ft pipeline. sW staging folds in the ePc factor; S is a column-sum
// of sW by wave-0 lanes 0-31 (conflict-free, hidden under other waves' FMAs).
__global__ __launch_bounds__(256) void k_G(const float* __restrict__ eRc,
                                           const float* __restrict__ ePc,
                                           const float* __restrict__ Ft,
                                           float* __restrict__ G,
                                           float* __restrict__ S) {
  __shared__ __align__(16) float sW[128 * 36];   // sW[p][a], stride 36: b128 align
  int bid = blockIdx.x;
  int at = bid % 12;
  int n  = (bid / 12) % NN_;
  int b  = bid / 240;
  int a0 = at << 5;                              // 32 a per block
  int tid = threadIdx.x;
  int w8 = (tid >> 6) << 3;                      // wave * 8 -> a offset
  int lane = tid & 63;
  int q  = lane >> 4;                            // 0..3 : p offset within 4-p step
  int c0 = (lane & 15) << 2;                     // c 0..60 (lo half), +64 (hi half)
  int kst = tid & 127, hst = tid >> 7;           // staging role: p, a-half
  float4 aL[8], aH[8];
  #pragma unroll
  for (int r = 0; r < 8; ++r) {
    aL[r] = make_float4(0.f, 0.f, 0.f, 0.f);
    aH[r] = make_float4(0.f, 0.f, 0.f, 0.f);
  }
  float sS = 0.f;
  const float* epc   = ePc + (b * NN_ + n) * P_;
  const float* fbase = Ft + ((size_t)(b * NN_ + n) * P_ + q) * C_ + c0;
  for (int pc0 = 0; pc0 < 256; pc0 += 128) {
    __syncthreads();                             // all waves done reading sW
    #pragma unroll
    for (int r = 0; r < 16; ++r) {               // 128 p x 32 a, 16 elems/thread
      int ar = a0 + hst * 16 + r;
      if (ar > 359) ar = 359;                    // clamp: in-bounds, unused rows
      sW[kst * 36 + hst * 16 + r] = eRc[ar * P_ + pc0 + kst] * epc[pc0 + kst];
    }
    __syncthreads();
    if (tid < 32) {                              // S partial: column a=tid of sW
      float t = 0.f;
      #pragma unroll 8
      for (int p = 0; p < 128; ++p) t += sW[p * 36 + tid];
      sS += t;
    }
    const float* fp  = fbase + (size_t)pc0 * C_;
    const float* swk = sW + q * 36 + w8;
#define FMA8(r, wgt, f0, f1) \
    aL[r].x += (wgt) * f0.x; aL[r].y += (wgt) * f0.y; \
    aL[r].z += (wgt) * f0.z; aL[r].w += (wgt) * f0.w; \
    aH[r].x += (wgt) * f1.x; aH[r].y += (wgt) * f1.y; \
    aH[r].z += (wgt) * f1.z; aH[r].w += (wgt) * f1.w;
#define FMA64(wa, wb, f0, f1) \
    FMA8(0, wa.x, f0, f1) FMA8(1, wa.y, f0, f1) FMA8(2, wa.z, f0, f1) \
    FMA8(3, wa.w, f0, f1) FMA8(4, wb.x, f0, f1) FMA8(5, wb.y, f0, f1) \
    FMA8(6, wb.z, f0, f1) FMA8(7, wb.w, f0, f1)
    float4 fa0 = *(const float4*)(fp);
    float4 fb0 = *(const float4*)(fp + 64);
    #pragma unroll
    for (int kk = 0; kk < 128; kk += 8) {
      float4 fa1 = *(const float4*)(fp + (size_t)(kk + 4) * C_);
      float4 fb1 = *(const float4*)(fp + (size_t)(kk + 4) * C_ + 64);
      float4 wa  = *(const float4*)(swk + kk * 36);
      float4 wb  = *(const float4*)(swk + kk * 36 + 4);
      FMA64(wa, wb, fa0, fb0)
      int pk = (kk + 8 < 128) ? (kk + 8) : 0;    // folds at compile time
      fa0 = *(const float4*)(fp + (size_t)pk * C_);
      fb0 = *(const float4*)(fp + (size_t)pk * C_ + 64);
      wa  = *(const float4*)(swk + (kk + 4) * 36);
      wb  = *(const float4*)(swk + (kk + 4) * 36 + 4);
      FMA64(wa, wb, fa1, fb1)
    }
#undef FMA64
#undef FMA8
  }
  // combine the 4 q-partials (lane bits 4,5)
#define RED2(v) { v += __shfl_xor(v, 16); v += __shfl_xor(v, 32); }
  #pragma unroll
  for (int r = 0; r < 8; ++r) {
    RED2(aL[r].x) RED2(aL[r].y) RED2(aL[r].z) RED2(aL[r].w)
    RED2(aH[r].x) RED2(aH[r].y) RED2(aH[r].z) RED2(aH[r].w)
  }
#undef RED2
  // q-group g writes a-rows {2g, 2g+1}
  #pragma unroll
  for (int r = 0; r < 8; ++r) {
    if ((r >> 1) == q) {
      int a = a0 + w8 + r;
      if (a < 360) {
        float* pt = G + (((size_t)b * 360 + a) * NN_ + n) * C_;
        *(float4*)(pt + c0)      = aL[r];
        *(float4*)(pt + c0 + 64) = aH[r];
      }
    }
  }
  if (tid < 32) {
    int a = a0 + tid;
    if (a < 360) S[((size_t)b * 360 + a) * NN_ + n] = sS;
  }
}

// Per grid cell: FACTORED attn + gf. No per-pixel logits, no reductions:
//   Z = sum_n e^{Ks}*S[i,n];  attn[n,p] = (e^{Ks_n}/Z)*eRc[i_n,p]*ePc[n,p];
//   gf[c] = sum_n (e^{Ks_n}/Z)*G[i_n,n,c].
// Shift-invariance is exact; logits are O(+-3) so unshifted exp is safe.
__global__ __launch_bounds__(256) void k_soft(const float* __restrict__ eRc,
                                              const float* __restrict__ ePc,
                                              const float* __restrict__ Kscal,
                                              const int* __restrict__ ind,
                                              const float* __restrict__ S,
                                              const float* __restrict__ G,
                                              float* __restrict__ attn,
                                              float* __restrict__ gf) {
  int bl = blockIdx.x;                           // b*L + l
  int b = bl >> 10;
  int tid = threadIdx.x;                         // pixel p
  __shared__ float sE[NN_];                      // e^{Ks}
  __shared__ int   sI[NN_];
  __shared__ float sZ[NN_];                      // e^{Ks} * S[i,n]
  if (tid < NN_) {
    int i = ind[bl * NN_ + tid];
    float ek = expf(Kscal[bl * NN_ + tid]);
    sI[tid] = i;
    sE[tid] = ek;
    sZ[tid] = ek * S[((size_t)b * 360 + i) * NN_ + tid];
  }
  __syncthreads();
  float Z = 0.f;
  #pragma unroll
  for (int n = 0; n < NN_; ++n) Z += sZ[n];
  float invZ = 1.0f / Z;
  #pragma unroll
  for (int n = 0; n < NN_; ++n) {
    float wn = sE[n] * invZ;
    attn[((size_t)bl * NN_ + n) * P_ + tid] =
        wn * eRc[sI[n] * P_ + tid] * ePc[(b * NN_ + n) * P_ + tid];
  }
  if (tid < C_) {                                // gf gather (G L2/L3-resident)
    float acc = 0.f;
    #pragma unroll
    for (int n = 0; n < NN_; ++n)
      acc += (sE[n] * invZ) * G[(((size_t)b * 360 + sI[n]) * NN_ + n) * C_ + tid];
    gf[(size_t)bl * C_ + tid] = acc;
  }
}

extern "C" void kernel_launch(void* const* d_in, const int* in_sizes, int n_in,
                              void* d_out, int out_size, void* d_ws, size_t ws_size,
                              hipStream_t stream) {
  const float* bbox  = (const float*)d_in[0];
  const float* locs  = (const float*)d_in[1];
  const float* feats = (const float*)d_in[2];
  const float* rays  = (const float*)d_in[4];
  const float* w1    = (const float*)d_in[5];
  const float* b1    = (const float*)d_in[6];
  const float* w2    = (const float*)d_in[7];
  const float* b2    = (const float*)d_in[8];
  const float* fw    = (const float*)d_in[9];
  const float* fb    = (const float*)d_in[10];

  float* ws     = (float*)d_ws;
  int*   ind    = (int*)ws;
  float* Kscal  = ws + 81920;
  float* eRc    = ws + 163840;
  float* ePc    = ws + 256000;
  float* S      = ws + 276480;
  float* Ft     = ws + 325632;
  float* G      = ws + 2947072;

  float* gf   = (float*)d_out;
  float* attn = gf + (B_ * L_ * C_);             // 20.97M floats

  k_front<<<1080, 256, 0, stream>>>(feats, rays, bbox, locs, w1, w2, b1, b2,
                                    fw, fb, eRc, ePc, ind, Kscal, Ft);
  k_G    <<<960, 256, 0, stream>>>(eRc, ePc, Ft, G, S);
  k_soft <<<4096, 256, 0, stream>>>(eRc, ePc, Kscal, ind, S, G, attn, gf);
}